// Round 4
// baseline (223.536 us; speedup 1.0000x reference)
//
#include <hip/hip_runtime.h>
#include <math.h>

// Problem constants (B=1)
#define TT   512
#define CEMB 768
#define NH   12
#define NKV  6
#define HD   64
#define KVC  (NKV*HD)   // 384

__device__ __forceinline__ float wave_sum(float v){
  #pragma unroll
  for(int o=32;o>0;o>>=1) v += __shfl_xor(v, o);
  return v;
}

// ---- fp32 GEMM: 1-wave block, 32x64 tile, BK=16, 8x4 microtile ----
// No __syncthreads at all (single wave => DS ops in order). Double-buffered
// LDS + global->reg prefetch hides latency via ILP.
__device__ __forceinline__ void gemm32x64(const float* __restrict__ A,
                                          const float* __restrict__ B,
                                          float* __restrict__ C,
                                          int K, int lda, int ldb, int ldc,
                                          int m0, int n0){
  __shared__ float As[2][16][36];   // [buf][k][m]
  __shared__ float Bs[2][16][68];   // [buf][k][n]
  int lane = threadIdx.x;
  int lg = lane >> 4;       // row group 0..3
  int lc = lane & 15;       // col group 0..15
  int ar = lane >> 1;       // staging: A row 0..31
  int ak = (lane & 1) * 8;  // staging: A k base

  float acc[8][4];
  #pragma unroll
  for(int r=0;r<8;r++)
    #pragma unroll
    for(int c=0;c<4;c++) acc[r][c] = 0.f;

  const float* Ap = A + (size_t)(m0+ar)*lda + ak;
  const float* Bp = B + n0;

  float4 a0 = *(const float4*)(Ap + 0);
  float4 a1 = *(const float4*)(Ap + 4);
  float4 bb[4];
  #pragma unroll
  for(int j=0;j<4;j++){
    int idx = lane + 64*j;
    bb[j] = *(const float4*)(Bp + (size_t)(idx>>4)*ldb + (idx&15)*4);
  }

  int buf = 0;
  for(int k0=0; k0<K; k0+=16){
    // commit prefetched tile to LDS[buf]
    As[buf][ak+0][ar]=a0.x; As[buf][ak+1][ar]=a0.y; As[buf][ak+2][ar]=a0.z; As[buf][ak+3][ar]=a0.w;
    As[buf][ak+4][ar]=a1.x; As[buf][ak+5][ar]=a1.y; As[buf][ak+6][ar]=a1.z; As[buf][ak+7][ar]=a1.w;
    #pragma unroll
    for(int j=0;j<4;j++){
      int idx = lane + 64*j;
      *(float4*)&Bs[buf][idx>>4][(idx&15)*4] = bb[j];
    }
    // prefetch next tile
    if (k0 + 16 < K){
      a0 = *(const float4*)(Ap + k0 + 16);
      a1 = *(const float4*)(Ap + k0 + 20);
      #pragma unroll
      for(int j=0;j<4;j++){
        int idx = lane + 64*j;
        bb[j] = *(const float4*)(Bp + (size_t)(k0+16+(idx>>4))*ldb + (idx&15)*4);
      }
    }
    // compute from LDS[buf]
    #pragma unroll
    for(int kk=0;kk<16;kk++){
      float4 av0 = *(float4*)&As[buf][kk][lg*4];
      float4 av1 = *(float4*)&As[buf][kk][lg*4+16];
      float4 bv  = *(float4*)&Bs[buf][kk][lc*4];
      #pragma unroll
      for(int r=0;r<4;r++){
        float a_lo = (&av0.x)[r], a_hi = (&av1.x)[r];
        #pragma unroll
        for(int c=0;c<4;c++){
          acc[r][c]   = fmaf(a_lo, (&bv.x)[c], acc[r][c]);
          acc[r+4][c] = fmaf(a_hi, (&bv.x)[c], acc[r+4][c]);
        }
      }
    }
    buf ^= 1;
  }
  #pragma unroll
  for(int r=0;r<8;r++){
    int row = m0 + lg*4 + (r&3) + (r>>2)*16;
    *(float4*)(C + (size_t)row*ldc + n0 + lc*4) =
      make_float4(acc[r][0],acc[r][1],acc[r][2],acc[r][3]);
  }
}

__global__ void __launch_bounds__(64) gemm_qkv(const float* __restrict__ X,
    const float* __restrict__ Wq, const float* __restrict__ Wk, const float* __restrict__ Wv,
    float* __restrict__ q, float* __restrict__ k, float* __restrict__ v){
  int mt = blockIdx.x;       // 0..15
  int nt = blockIdx.y;       // 0..23
  const float* B; float* C; int ldb, ldc, n0;
  if (nt < 12)      { B = Wq; C = q; ldb = CEMB; ldc = CEMB; n0 = nt*64; }
  else if (nt < 18) { B = Wk; C = k; ldb = KVC;  ldc = KVC;  n0 = (nt-12)*64; }
  else              { B = Wv; C = v; ldb = KVC;  ldc = KVC;  n0 = (nt-18)*64; }
  gemm32x64(X, B, C, CEMB, CEMB, ldb, ldc, mt*32, n0);
}

__global__ void __launch_bounds__(64) gemm_proj(const float* __restrict__ Y,
    const float* __restrict__ Wp, float* __restrict__ C){
  gemm32x64(Y, Wp, C, CEMB, CEMB, CEMB, CEMB, blockIdx.x*32, blockIdx.y*64);
}

// RoPE + RMSNorm, in-place on q (512x768) and k (512x384). One wave = one (t, head).
__global__ void __launch_bounds__(256) rope_rms(float* __restrict__ q, float* __restrict__ k,
    const float* __restrict__ cosb, const float* __restrict__ sinb){
  int wid  = (blockIdx.x * blockDim.x + threadIdx.x) >> 6;
  int lane = threadIdx.x & 63;
  float* base; int t;
  if (wid < TT*NH){
    t = wid / NH; int h = wid % NH;
    base = q + (size_t)t*CEMB + h*HD;
  } else {
    int w2 = wid - TT*NH;
    t = w2 / NKV; int h = w2 % NKV;
    base = k + (size_t)t*KVC + h*HD;
  }
  float v = base[lane];
  int dh = lane & 31;
  float c = cosb[t*32 + dh];
  float s = sinb[t*32 + dh];
  float partner = __shfl_xor(v, 32);
  float rot = (lane < 32) ? (v*c - partner*s) : (v*c + partner*s);
  float ss = wave_sum(rot*rot);
  float scale = rsqrtf(ss * (1.0f/64.0f) + 1e-6f);
  base[lane] = rot * scale;
}

// ---- Register-tiled split-KV tropical attention ----
// Block = (h, qt: 64 q-rows, ct: 128 kv rows = <=2 tiles). 240 blocks, 64KB LDS
// => all blocks co-resident. Wave w owns q-rows qt*64 + w*16..+15.
// Lane microtile: 4 rows (lane>>4 group) x 4 cols (lane&15 group).
// K/V in LDS with 16B XOR swizzle keyed on row>>2 (== lane&15 at read time)
// => all reads spread over 8 bank-groups (2-way, free).
__global__ void __launch_bounds__(256) attn_partial(const float* __restrict__ qn,
    const float* __restrict__ kn, const float* __restrict__ vr,
    float* __restrict__ part_acc, float2* __restrict__ part_ml){
  __shared__ float Qsh[64*64];
  __shared__ float Ksh[64*64];
  __shared__ float Vsh[64*64];
  __shared__ float Psh[64*64];

  int h   = blockIdx.y;
  int idx = blockIdx.x;        // 0..19 -> (qt, ct); counts per qt: 1,1,2,2,3,3,4,4
  int qt, ct;
  if      (idx < 1) { qt=0; ct=idx;    }
  else if (idx < 2) { qt=1; ct=idx-1;  }
  else if (idx < 4) { qt=2; ct=idx-2;  }
  else if (idx < 6) { qt=3; ct=idx-4;  }
  else if (idx < 9) { qt=4; ct=idx-6;  }
  else if (idx < 12){ qt=5; ct=idx-9;  }
  else if (idx < 16){ qt=6; ct=idx-12; }
  else              { qt=7; ct=idx-16; }

  int kvh  = h >> 1;
  int w    = threadIdx.x >> 6;
  int lane = threadIdx.x & 63;
  int lg   = lane >> 4;        // row group 0..3
  int lc   = lane & 15;        // col group 0..15

  // stage Q (wave-local rows; read only by this wave)
  #pragma unroll
  for(int sub=0; sub<4; ++sub){
    int rr = w*16 + sub*4 + lg;
    *(float4*)&Qsh[rr*64 + lc*4] =
      *(const float4*)&qn[(size_t)(qt*64+rr)*CEMB + h*HD + lc*4];
  }

  float m_run[4], l_run[4], acc[4][4];
  #pragma unroll
  for(int r=0;r<4;r++){
    m_run[r] = -INFINITY; l_run[r] = 0.f;
    #pragma unroll
    for(int c=0;c<4;c++) acc[r][c] = 0.f;
  }

  int ntiles = (2*ct < qt) ? 2 : 1;

  for(int tt=0; tt<ntiles; ++tt){
    int t0 = ct*128 + tt*64;
    __syncthreads();                       // protect K/V (re)stage
    #pragma unroll
    for(int sub=0; sub<4; ++sub){
      int rr = w*16 + sub*4 + lg;
      int sw = ((lc ^ (rr>>2)) & 15)*4;
      *(float4*)&Ksh[rr*64 + sw] =
        *(const float4*)&kn[(size_t)(t0+rr)*KVC + kvh*HD + lc*4];
      *(float4*)&Vsh[rr*64 + sw] =
        *(const float4*)&vr[(size_t)(t0+rr)*KVC + kvh*HD + lc*4];
    }
    __syncthreads();

    // scores: s[r][c] = max_d q[row_r][d] + k[col_c][d]
    float s[4][4];
    #pragma unroll
    for(int r=0;r<4;r++)
      #pragma unroll
      for(int c=0;c<4;c++) s[r][c] = -INFINITY;

    #pragma unroll
    for(int dg=0; dg<16; ++dg){
      float4 k4[4], q4[4];
      int ksw = ((dg ^ lc)&15)*4;
      #pragma unroll
      for(int c=0;c<4;c++)
        k4[c] = *(const float4*)&Ksh[(lc*4+c)*64 + ksw];
      #pragma unroll
      for(int r=0;r<4;r++)
        q4[r] = *(const float4*)&Qsh[(w*16+lg*4+r)*64 + dg*4];
      #pragma unroll
      for(int r=0;r<4;r++)
        #pragma unroll
        for(int c=0;c<4;c++)
          s[r][c] = fmaxf(s[r][c],
                    fmaxf(fmaxf(q4[r].x + k4[c].x, q4[r].y + k4[c].y),
                          fmaxf(q4[r].z + k4[c].z, q4[r].w + k4[c].w)));
    }

    // per-row softmax partial + P to LDS (wave-private rows)
    #pragma unroll
    for(int r=0;r<4;r++){
      int i = qt*64 + w*16 + lg*4 + r;
      #pragma unroll
      for(int c=0;c<4;c++)
        if (t0 + lc*4 + c > i) s[r][c] = -INFINITY;   // causal mask
      float mt = fmaxf(fmaxf(s[r][0],s[r][1]), fmaxf(s[r][2],s[r][3]));
      mt = fmaxf(mt, __shfl_xor(mt,1));
      mt = fmaxf(mt, __shfl_xor(mt,2));
      mt = fmaxf(mt, __shfl_xor(mt,4));
      mt = fmaxf(mt, __shfl_xor(mt,8));
      float m_new = fmaxf(m_run[r], mt);
      float mb    = (m_new == -INFINITY) ? 0.f : m_new;
      float corr  = __expf(m_run[r] - mb);
      float p0 = __expf(s[r][0]-mb), p1 = __expf(s[r][1]-mb);
      float p2 = __expf(s[r][2]-mb), p3 = __expf(s[r][3]-mb);
      float ps = p0+p1+p2+p3;
      ps += __shfl_xor(ps,1); ps += __shfl_xor(ps,2);
      ps += __shfl_xor(ps,4); ps += __shfl_xor(ps,8);
      l_run[r] = l_run[r]*corr + ps;
      #pragma unroll
      for(int c=0;c<4;c++) acc[r][c] *= corr;
      m_run[r] = m_new;
      *(float4*)&Psh[(w*16+lg*4+r)*64 + lc*4] = make_float4(p0,p1,p2,p3);
    }
    __builtin_amdgcn_wave_barrier();

    // PV: acc[r][c] += sum_j P[row_r][j] * V[j][col_c]
    #pragma unroll
    for(int jg=0; jg<16; ++jg){
      float4 v4[4];
      int vsw = ((lc ^ jg)&15)*4;
      #pragma unroll
      for(int jj=0;jj<4;jj++)
        v4[jj] = *(const float4*)&Vsh[(jg*4+jj)*64 + vsw];
      #pragma unroll
      for(int r=0;r<4;r++){
        float4 p4 = *(const float4*)&Psh[(w*16+lg*4+r)*64 + jg*4];
        #pragma unroll
        for(int c=0;c<4;c++)
          acc[r][c] = fmaf(p4.x, (&v4[0].x)[c], fmaf(p4.y, (&v4[1].x)[c],
                      fmaf(p4.z, (&v4[2].x)[c], fmaf(p4.w, (&v4[3].x)[c], acc[r][c]))));
      }
    }
    __builtin_amdgcn_wave_barrier();
  }

  #pragma unroll
  for(int r=0;r<4;r++){
    int i = qt*64 + w*16 + lg*4 + r;
    int pidx = (h*TT + i)*4 + ct;
    *(float4*)&part_acc[(size_t)pidx*64 + lc*4] =
      make_float4(acc[r][0],acc[r][1],acc[r][2],acc[r][3]);
    if (lc == 0) part_ml[pidx] = make_float2(m_run[r], l_run[r]);
  }
}

// Merge <=4 chunk partials per (h, row). One wave per row.
__global__ void __launch_bounds__(256) attn_reduce(const float* __restrict__ part_acc,
    const float2* __restrict__ part_ml, float* __restrict__ y){
  int wid  = (blockIdx.x * blockDim.x + threadIdx.x) >> 6;  // 0..6143
  int lane = threadIdx.x & 63;
  int h = wid >> 9;
  int i = wid & 511;
  int nch = (i >> 7) + 1;
  float m = -INFINITY, l = 0.f, a = 0.f;
  for(int c=0;c<nch;c++){
    int pidx = (h*TT + i)*4 + c;
    float2 ml = part_ml[pidx];
    float ac  = part_acc[(size_t)pidx*64 + lane];
    float m_new = fmaxf(m, ml.x);
    float sa  = __expf(m - m_new);
    float sc_ = __expf(ml.x - m_new);
    l = l*sa + ml.y*sc_;
    a = a*sa + ac*sc_;
    m = m_new;
  }
  y[(size_t)i*CEMB + h*HD + lane] = a / l;
}

extern "C" void kernel_launch(void* const* d_in, const int* in_sizes, int n_in,
                              void* d_out, int out_size, void* d_ws, size_t ws_size,
                              hipStream_t stream){
  const float* x    = (const float*)d_in[0];
  const float* cosb = (const float*)d_in[1];
  const float* sinb = (const float*)d_in[2];
  const float* Wq   = (const float*)d_in[3];
  const float* Wk   = (const float*)d_in[4];
  const float* Wv   = (const float*)d_in[5];
  const float* Wp   = (const float*)d_in[6];
  float* out = (float*)d_out;

  float* ws       = (float*)d_ws;
  float* q_raw    = ws;                          // 512*768
  float* k_raw    = q_raw + TT*CEMB;             // 512*384
  float* v_raw    = k_raw + TT*KVC;              // 512*384
  float* ybuf     = v_raw + TT*KVC;              // 512*768
  float* part_acc = ybuf + TT*CEMB;              // 12*512*4*64
  float2* part_ml = (float2*)(part_acc + (size_t)NH*TT*4*64);  // 12*512*4

  gemm_qkv    <<<dim3(16,24), 64, 0, stream>>>(x, Wq, Wk, Wv, q_raw, k_raw, v_raw);
  rope_rms    <<<dim3((TT*NH + TT*NKV)/4), 256, 0, stream>>>(q_raw, k_raw, cosb, sinb);
  attn_partial<<<dim3(20, NH), 256, 0, stream>>>(q_raw, k_raw, v_raw, part_acc, part_ml);
  attn_reduce <<<dim3(NH*TT/4), 256, 0, stream>>>(part_acc, part_ml, ybuf);
  gemm_proj   <<<dim3(16,12), 64, 0, stream>>>(ybuf, Wp, out);
}

// Round 5
// 136.864 us; speedup vs baseline: 1.6333x; 1.6333x over previous
//
#include <hip/hip_runtime.h>
#include <math.h>

// Problem constants (B=1)
#define TT   512
#define CEMB 768
#define NH   12
#define NKV  6
#define HD   64
#define KVC  (NKV*HD)   // 384
#define NTOT 1536       // q(768) | k(384) | v(384)

__device__ __forceinline__ float wave_sum(float v){
  #pragma unroll
  for(int o=32;o>0;o>>=1) v += __shfl_xor(v, o);
  return v;
}

// ---- fp32 GEMM partial: 64x64 tile, BK=16, 256 threads, 4x4 microtile ----
// Split-K: this block accumulates A[m0:m0+64, kbeg:kbeg+klen] @ B[.., n] into
// a per-split partial buffer. Double-buffered LDS + global->reg prefetch.
__device__ __forceinline__ void gemm_sk(const float* __restrict__ A,
                                        const float* __restrict__ B,
                                        float* __restrict__ P,
                                        int lda, int ldb, int ldc,
                                        int m0, int bcol, int pcol,
                                        int kbeg, int klen){
  __shared__ float As[2][16][68];   // [buf][k][m] pad 68: stores 2-way max
  __shared__ float Bs[2][16][68];   // [buf][k][n]
  int tid  = threadIdx.x;
  int arow = tid >> 2, ak4 = (tid & 3) * 4;   // A stage: 64 m x 16 k
  int brow = tid >> 4, bc  = (tid & 15) * 4;  // B stage: 16 k x 64 n
  int ty   = tid >> 4, tx = tid & 15;         // micro: rows ty*4..+3, cols tx*4..+3

  float acc[4][4];
  #pragma unroll
  for(int i=0;i<4;i++)
    #pragma unroll
    for(int j=0;j<4;j++) acc[i][j] = 0.f;

  const float* Ap = A + (size_t)(m0+arow)*lda + kbeg + ak4;
  const float* Bq = B + (size_t)(kbeg+brow)*ldb + bcol + bc;

  float4 a = *(const float4*)(Ap);
  float4 b = *(const float4*)(Bq);

  int buf = 0;
  for(int k0=0; k0<klen; k0+=16){
    As[buf][ak4+0][arow]=a.x; As[buf][ak4+1][arow]=a.y;
    As[buf][ak4+2][arow]=a.z; As[buf][ak4+3][arow]=a.w;
    *(float4*)&Bs[buf][brow][bc] = b;
    if (k0 + 16 < klen){
      a = *(const float4*)(Ap + k0 + 16);
      b = *(const float4*)(Bq + (size_t)(k0+16)*ldb);
    }
    __syncthreads();
    #pragma unroll
    for(int kk=0;kk<16;kk++){
      float4 av = *(float4*)&As[buf][kk][ty*4];
      float4 bv = *(float4*)&Bs[buf][kk][tx*4];
      #pragma unroll
      for(int r=0;r<4;r++)
        #pragma unroll
        for(int c=0;c<4;c++)
          acc[r][c] = fmaf((&av.x)[r], (&bv.x)[c], acc[r][c]);
    }
    buf ^= 1;
    // next iter writes other buffer; barrier above ensures stores visible
  }
  #pragma unroll
  for(int r=0;r<4;r++)
    *(float4*)(P + (size_t)(m0+ty*4+r)*ldc + pcol + tx*4) =
      make_float4(acc[r][0],acc[r][1],acc[r][2],acc[r][3]);
}

// QKV: X(512x768) @ [Wq|Wk|Wv] -> partials[ks][512][1536], splitK=4 (K=192 each)
__global__ void __launch_bounds__(256) gemm_qkv_partial(const float* __restrict__ X,
    const float* __restrict__ Wq, const float* __restrict__ Wk, const float* __restrict__ Wv,
    float* __restrict__ P){
  int mt = blockIdx.x;   // 0..7
  int nt = blockIdx.y;   // 0..23
  int ks = blockIdx.z;   // 0..3
  const float* B; int ldb, bcol;
  if (nt < 12)      { B = Wq; ldb = CEMB; bcol = nt*64; }
  else if (nt < 18) { B = Wk; ldb = KVC;  bcol = (nt-12)*64; }
  else              { B = Wv; ldb = KVC;  bcol = (nt-18)*64; }
  gemm_sk(X, B, P + (size_t)ks*TT*NTOT, CEMB, ldb, NTOT,
          mt*64, bcol, nt*64, ks*192, 192);
}

// Proj: Y(512x768) @ Wproj -> partials[ks][512][768], splitK=4
__global__ void __launch_bounds__(256) gemm_proj_partial(const float* __restrict__ Y,
    const float* __restrict__ Wp, float* __restrict__ P){
  gemm_sk(Y, Wp, P + (size_t)blockIdx.z*TT*CEMB, CEMB, CEMB, CEMB,
          blockIdx.x*64, blockIdx.y*64, blockIdx.y*64, blockIdx.z*192, 192);
}

// Merge 4 qkv partials + fused RoPE + RMSNorm. One wave per (t, 64-col slot).
// Slots 0..11 = q heads, 12..17 = k heads, 18..23 = v heads.
__global__ void __launch_bounds__(256) merge_qkv(const float* __restrict__ P,
    const float* __restrict__ cosb, const float* __restrict__ sinb,
    float* __restrict__ q, float* __restrict__ k, float* __restrict__ v){
  int wid  = (blockIdx.x * blockDim.x + threadIdx.x) >> 6;  // 0..12287
  int lane = threadIdx.x & 63;
  int t    = wid / 24;
  int slot = wid - t*24;
  size_t base = (size_t)t*NTOT + slot*64 + lane;
  float sum = P[base] + P[base + (size_t)TT*NTOT] +
              P[base + (size_t)2*TT*NTOT] + P[base + (size_t)3*TT*NTOT];
  if (slot < 18){
    float c = cosb[t*32 + (lane&31)];
    float s = sinb[t*32 + (lane&31)];
    float partner = __shfl_xor(sum, 32);
    float rot = (lane < 32) ? (sum*c - partner*s) : (sum*c + partner*s);
    float ss = wave_sum(rot*rot);
    float val = rot * rsqrtf(ss * (1.0f/64.0f) + 1e-6f);
    if (slot < 12) q[(size_t)t*CEMB + slot*64 + lane] = val;
    else           k[(size_t)t*KVC + (slot-12)*64 + lane] = val;
  } else {
    v[(size_t)t*KVC + (slot-18)*64 + lane] = sum;
  }
}

// Merge 4 proj partials -> out. float4 per thread.
__global__ void __launch_bounds__(256) merge_out(const float* __restrict__ P,
    float* __restrict__ out){
  int i = (blockIdx.x * blockDim.x + threadIdx.x) * 4;   // < 512*768
  float4 a = *(const float4*)(P + i);
  float4 b = *(const float4*)(P + i + (size_t)TT*CEMB);
  float4 c = *(const float4*)(P + i + (size_t)2*TT*CEMB);
  float4 d = *(const float4*)(P + i + (size_t)3*TT*CEMB);
  *(float4*)(out + i) = make_float4(a.x+b.x+c.x+d.x, a.y+b.y+c.y+d.y,
                                    a.z+b.z+c.z+d.z, a.w+b.w+c.w+d.w);
}

// ---- Register-tiled split-KV tropical attention (R3, unchanged) ----
__global__ void __launch_bounds__(256) attn_partial(const float* __restrict__ qn,
    const float* __restrict__ kn, const float* __restrict__ vr,
    float* __restrict__ part_acc, float2* __restrict__ part_ml){
  __shared__ float Qsh[64*64];
  __shared__ float Ksh[64*64];
  __shared__ float Vsh[64*64];
  __shared__ float Psh[64*64];

  int h   = blockIdx.y;
  int idx = blockIdx.x;        // 0..19 -> (qt, ct); counts per qt: 1,1,2,2,3,3,4,4
  int qt, ct;
  if      (idx < 1) { qt=0; ct=idx;    }
  else if (idx < 2) { qt=1; ct=idx-1;  }
  else if (idx < 4) { qt=2; ct=idx-2;  }
  else if (idx < 6) { qt=3; ct=idx-4;  }
  else if (idx < 9) { qt=4; ct=idx-6;  }
  else if (idx < 12){ qt=5; ct=idx-9;  }
  else if (idx < 16){ qt=6; ct=idx-12; }
  else              { qt=7; ct=idx-16; }

  int kvh  = h >> 1;
  int w    = threadIdx.x >> 6;
  int lane = threadIdx.x & 63;
  int lg   = lane >> 4;
  int lc   = lane & 15;

  #pragma unroll
  for(int sub=0; sub<4; ++sub){
    int rr = w*16 + sub*4 + lg;
    *(float4*)&Qsh[rr*64 + lc*4] =
      *(const float4*)&qn[(size_t)(qt*64+rr)*CEMB + h*HD + lc*4];
  }

  float m_run[4], l_run[4], acc[4][4];
  #pragma unroll
  for(int r=0;r<4;r++){
    m_run[r] = -INFINITY; l_run[r] = 0.f;
    #pragma unroll
    for(int c=0;c<4;c++) acc[r][c] = 0.f;
  }

  int ntiles = (2*ct < qt) ? 2 : 1;

  for(int tt=0; tt<ntiles; ++tt){
    int t0 = ct*128 + tt*64;
    __syncthreads();
    #pragma unroll
    for(int sub=0; sub<4; ++sub){
      int rr = w*16 + sub*4 + lg;
      int sw = ((lc ^ (rr>>2)) & 15)*4;
      *(float4*)&Ksh[rr*64 + sw] =
        *(const float4*)&kn[(size_t)(t0+rr)*KVC + kvh*HD + lc*4];
      *(float4*)&Vsh[rr*64 + sw] =
        *(const float4*)&vr[(size_t)(t0+rr)*KVC + kvh*HD + lc*4];
    }
    __syncthreads();

    float s[4][4];
    #pragma unroll
    for(int r=0;r<4;r++)
      #pragma unroll
      for(int c=0;c<4;c++) s[r][c] = -INFINITY;

    #pragma unroll
    for(int dg=0; dg<16; ++dg){
      float4 k4[4], q4[4];
      int ksw = ((dg ^ lc)&15)*4;
      #pragma unroll
      for(int c=0;c<4;c++)
        k4[c] = *(const float4*)&Ksh[(lc*4+c)*64 + ksw];
      #pragma unroll
      for(int r=0;r<4;r++)
        q4[r] = *(const float4*)&Qsh[(w*16+lg*4+r)*64 + dg*4];
      #pragma unroll
      for(int r=0;r<4;r++)
        #pragma unroll
        for(int c=0;c<4;c++)
          s[r][c] = fmaxf(s[r][c],
                    fmaxf(fmaxf(q4[r].x + k4[c].x, q4[r].y + k4[c].y),
                          fmaxf(q4[r].z + k4[c].z, q4[r].w + k4[c].w)));
    }

    #pragma unroll
    for(int r=0;r<4;r++){
      int i = qt*64 + w*16 + lg*4 + r;
      #pragma unroll
      for(int c=0;c<4;c++)
        if (t0 + lc*4 + c > i) s[r][c] = -INFINITY;
      float mt = fmaxf(fmaxf(s[r][0],s[r][1]), fmaxf(s[r][2],s[r][3]));
      mt = fmaxf(mt, __shfl_xor(mt,1));
      mt = fmaxf(mt, __shfl_xor(mt,2));
      mt = fmaxf(mt, __shfl_xor(mt,4));
      mt = fmaxf(mt, __shfl_xor(mt,8));
      float m_new = fmaxf(m_run[r], mt);
      float mb    = (m_new == -INFINITY) ? 0.f : m_new;
      float corr  = __expf(m_run[r] - mb);
      float p0 = __expf(s[r][0]-mb), p1 = __expf(s[r][1]-mb);
      float p2 = __expf(s[r][2]-mb), p3 = __expf(s[r][3]-mb);
      float ps = p0+p1+p2+p3;
      ps += __shfl_xor(ps,1); ps += __shfl_xor(ps,2);
      ps += __shfl_xor(ps,4); ps += __shfl_xor(ps,8);
      l_run[r] = l_run[r]*corr + ps;
      #pragma unroll
      for(int c=0;c<4;c++) acc[r][c] *= corr;
      m_run[r] = m_new;
      *(float4*)&Psh[(w*16+lg*4+r)*64 + lc*4] = make_float4(p0,p1,p2,p3);
    }
    __builtin_amdgcn_wave_barrier();

    #pragma unroll
    for(int jg=0; jg<16; ++jg){
      float4 v4[4];
      int vsw = ((lc ^ jg)&15)*4;
      #pragma unroll
      for(int jj=0;jj<4;jj++)
        v4[jj] = *(const float4*)&Vsh[(jg*4+jj)*64 + vsw];
      #pragma unroll
      for(int r=0;r<4;r++){
        float4 p4 = *(const float4*)&Psh[(w*16+lg*4+r)*64 + jg*4];
        #pragma unroll
        for(int c=0;c<4;c++)
          acc[r][c] = fmaf(p4.x, (&v4[0].x)[c], fmaf(p4.y, (&v4[1].x)[c],
                      fmaf(p4.z, (&v4[2].x)[c], fmaf(p4.w, (&v4[3].x)[c], acc[r][c]))));
      }
    }
    __builtin_amdgcn_wave_barrier();
  }

  #pragma unroll
  for(int r=0;r<4;r++){
    int i = qt*64 + w*16 + lg*4 + r;
    int pidx = (h*TT + i)*4 + ct;
    *(float4*)&part_acc[(size_t)pidx*64 + lc*4] =
      make_float4(acc[r][0],acc[r][1],acc[r][2],acc[r][3]);
    if (lc == 0) part_ml[pidx] = make_float2(m_run[r], l_run[r]);
  }
}

// Merge <=4 chunk partials per (h, row). One wave per row.
__global__ void __launch_bounds__(256) attn_reduce(const float* __restrict__ part_acc,
    const float2* __restrict__ part_ml, float* __restrict__ y){
  int wid  = (blockIdx.x * blockDim.x + threadIdx.x) >> 6;  // 0..6143
  int lane = threadIdx.x & 63;
  int h = wid >> 9;
  int i = wid & 511;
  int nch = (i >> 7) + 1;
  float m = -INFINITY, l = 0.f, a = 0.f;
  for(int c=0;c<nch;c++){
    int pidx = (h*TT + i)*4 + c;
    float2 ml = part_ml[pidx];
    float ac  = part_acc[(size_t)pidx*64 + lane];
    float m_new = fmaxf(m, ml.x);
    float sa  = __expf(m - m_new);
    float sc_ = __expf(ml.x - m_new);
    l = l*sa + ml.y*sc_;
    a = a*sa + ac*sc_;
    m = m_new;
  }
  y[(size_t)i*CEMB + h*HD + lane] = a / l;
}

extern "C" void kernel_launch(void* const* d_in, const int* in_sizes, int n_in,
                              void* d_out, int out_size, void* d_ws, size_t ws_size,
                              hipStream_t stream){
  const float* x    = (const float*)d_in[0];
  const float* cosb = (const float*)d_in[1];
  const float* sinb = (const float*)d_in[2];
  const float* Wq   = (const float*)d_in[3];
  const float* Wk   = (const float*)d_in[4];
  const float* Wv   = (const float*)d_in[5];
  const float* Wp   = (const float*)d_in[6];
  float* out = (float*)d_out;

  float* ws       = (float*)d_ws;
  float* q_raw    = ws;                          // 512*768
  float* k_raw    = q_raw + TT*CEMB;             // 512*384
  float* v_raw    = k_raw + TT*KVC;              // 512*384
  float* ybuf     = v_raw + TT*KVC;              // 512*768
  float* part_acc = ybuf + TT*CEMB;              // 12*512*4*64
  float2* part_ml = (float2*)(part_acc + (size_t)NH*TT*4*64);  // 12*512*4
  float* gpart    = (float*)(part_ml + NH*TT*4); // 4*512*1536 (shared qkv/proj)

  gemm_qkv_partial <<<dim3(8,24,4), 256, 0, stream>>>(x, Wq, Wk, Wv, gpart);
  merge_qkv        <<<dim3(3072),   256, 0, stream>>>(gpart, cosb, sinb, q_raw, k_raw, v_raw);
  attn_partial     <<<dim3(20,NH),  256, 0, stream>>>(q_raw, k_raw, v_raw, part_acc, part_ml);
  attn_reduce      <<<dim3(NH*TT/4),256, 0, stream>>>(part_acc, part_ml, ybuf);
  gemm_proj_partial<<<dim3(8,12,4), 256, 0, stream>>>(ybuf, Wp, gpart);
  merge_out        <<<dim3(TT*CEMB/1024), 256, 0, stream>>>(gpart, out);
}